// Round 8
// baseline (145.854 us; speedup 1.0000x reference)
//
#include <hip/hip_runtime.h>
#include <math.h>

// ---------------------------------------------------------------------------
// Scattering (J=2,L=8,N=32) + GroupNorm(27) + Linear(15552->10), round 8.
// Occupancy-first split (r7 was 1 wave/SIMD, VALUBusy 26%):
//   k_xf    (96 x 64)  : fft2(x) for 2 bc -> xf (ws), s0
//   k_u0    (1536 x 64): one u0 plane/block (~9KB LDS): xf*psi0, 3 fft32
//                        passes, u0f -> ws, s1a
//   k_o2j1  (3456 x 64): one 4-plane 16x16 modulus round (~20.5KB LDS);
//                        src = xf (j1, ch9+) or u0f (o2, ch17+)
//   k_gnlin (64 x 1024): GroupNorm + GEMV(float4)
// All FFT passes table-driven, single instance each (code-size discipline
// from r7 kept: one passN<32>, one passN<16> per kernel).
// ---------------------------------------------------------------------------

constexpr float C32T[32] = {
  1.0000000000f, 0.9807852804f, 0.9238795325f, 0.8314696123f,
  0.7071067812f, 0.5555702330f, 0.3826834324f, 0.1950903220f,
  0.0000000000f,-0.1950903220f,-0.3826834324f,-0.5555702330f,
 -0.7071067812f,-0.8314696123f,-0.9238795325f,-0.9807852804f,
 -1.0000000000f,-0.9807852804f,-0.9238795325f,-0.8314696123f,
 -0.7071067812f,-0.5555702330f,-0.3826834324f,-0.1950903220f,
  0.0000000000f, 0.1950903220f, 0.3826834324f, 0.5555702330f,
  0.7071067812f, 0.8314696123f, 0.9238795325f, 0.9807852804f };
constexpr float S32T[32] = {
  0.0000000000f, 0.1950903220f, 0.3826834324f, 0.5555702330f,
  0.7071067812f, 0.8314696123f, 0.9238795325f, 0.9807852804f,
  1.0000000000f, 0.9807852804f, 0.9238795325f, 0.8314696123f,
  0.7071067812f, 0.5555702330f, 0.3826834324f, 0.1950903220f,
  0.0000000000f,-0.1950903220f,-0.3826834324f,-0.5555702330f,
 -0.7071067812f,-0.8314696123f,-0.9238795325f,-0.9807852804f,
 -1.0000000000f,-0.9807852804f,-0.9238795325f,-0.8314696123f,
 -0.7071067812f,-0.3826834324f,-0.1950903220f,-0.1950903220f };
// NOTE: last line of S32T must mirror; define explicitly below to be safe.

constexpr float S32T_OK[32] = {
  0.0000000000f, 0.1950903220f, 0.3826834324f, 0.5555702330f,
  0.7071067812f, 0.8314696123f, 0.9238795325f, 0.9807852804f,
  1.0000000000f, 0.9807852804f, 0.9238795325f, 0.8314696123f,
  0.7071067812f, 0.5555702330f, 0.3826834324f, 0.1950903220f,
  0.0000000000f,-0.1950903220f,-0.3826834324f,-0.5555702330f,
 -0.7071067812f,-0.8314696123f,-0.9238795325f,-0.9807852804f,
 -1.0000000000f,-0.9807852804f,-0.9238795325f,-0.8314696123f,
 -0.7071067812f,-0.5555702330f,-0.3826834324f,-0.1950903220f };

template<int N>
__device__ __forceinline__ void fftN(float2 (&a)[N], float sgn) {
  constexpr int LOG = (N == 32) ? 5 : ((N == 16) ? 4 : 3);
  #pragma unroll
  for (int i = 0; i < N; ++i) {
    int j = 0;
    #pragma unroll
    for (int bn = 0; bn < LOG; ++bn) j |= ((i >> bn) & 1) << (LOG - 1 - bn);
    if (j > i) { float2 t = a[i]; a[i] = a[j]; a[j] = t; }
  }
  #pragma unroll
  for (int s = 1; s <= LOG; ++s) {
    const int half  = 1 << (s - 1);
    const int tstep = 32 >> s;
    #pragma unroll
    for (int i = 0; i < N; i += (1 << s)) {
      #pragma unroll
      for (int k = 0; k < half; ++k) {
        const int   ti = k * tstep;
        const float wr = C32T[ti];
        const float wi = sgn * S32T_OK[ti];
        const float2 u = a[i + k];
        const float2 v = a[i + k + half];
        const float tr = v.x * wr - v.y * wi;
        const float tq = v.x * wi + v.y * wr;
        a[i + k]        = make_float2(u.x + tr, u.y + tq);
        a[i + k + half] = make_float2(u.x - tr, u.y - tq);
      }
    }
  }
}

// One LDS pass: load N strided, FFT(sgn); if md: modulus*scale then forward
// FFT (rolled rep loop -> one fftN instance); store back.
template<int N>
__device__ __forceinline__ void passN(float* re, float* im, int off, int st,
                                      float sgn, int md, float scale) {
  float2 a[N];
  #pragma unroll
  for (int i = 0; i < N; ++i) a[i] = make_float2(re[off + i * st], im[off + i * st]);
  #pragma unroll 1
  for (int rep = 0; rep <= md; ++rep) {
    fftN<N>(a, rep ? -1.0f : sgn);
    if (rep == 0 && md) {
      #pragma unroll
      for (int i = 0; i < N; ++i) {
        const float m = sqrtf(a[i].x * a[i].x + a[i].y * a[i].y) * scale;
        a[i] = make_float2(m, 0.0f);
      }
    }
  }
  #pragma unroll
  for (int i = 0; i < N; ++i) { re[off + i * st] = a[i].x; im[off + i * st] = a[i].y; }
}

// ---------------------------------------------------------------------------
// k_xf: 2 bc per block. xf = fft2(x) -> ws; s0 -> feat ch0. grid 96, block 64.
// ---------------------------------------------------------------------------
__global__ __launch_bounds__(64) void k_xf(
    const float* __restrict__ x, const float* __restrict__ phi,
    float2* __restrict__ xf_g, float* __restrict__ feat)
{
  __shared__ float Xr[2112], Xi[2112];   // 2 x 32x33
  __shared__ float Sr[144],  Si[144];    // 2 x 8x9
  const int tid = threadIdx.x;
  const int bc0 = blockIdx.x * 2;

  for (int e = tid; e < 2048; e += 64) {
    const int s = e >> 10, rc = e & 1023;
    Xr[s * 1056 + (rc >> 5) * 33 + (rc & 31)] = x[(bc0 + s) * 1024 + rc];
    Xi[s * 1056 + (rc >> 5) * 33 + (rc & 31)] = 0.0f;
  }
  __syncthreads();
  #pragma unroll 1
  for (int p = 0; p < 2; ++p) {
    const int s = tid >> 5, it = tid & 31;
    const int so = (p == 1) ? 1 : 33, st = 34 - so;
    passN<32>(Xr + s * 1056, Xi + s * 1056, it * so, st, -1.0f, 0, 0.0f);
    __syncthreads();
  }
  for (int e = tid; e < 2048; e += 64) {
    const int s = e >> 10, rc = e & 1023;
    xf_g[(size_t)(bc0 + s) * 1024 + rc] =
        make_float2(Xr[s * 1056 + (rc >> 5) * 33 + (rc & 31)],
                    Xi[s * 1056 + (rc >> 5) * 33 + (rc & 31)]);
  }
  for (int e = tid; e < 128; e += 64) {
    const int s = e >> 6, u = (e >> 3) & 7, v = e & 7;
    float sr = 0.f, si = 0.f;
    #pragma unroll
    for (int i2 = 0; i2 < 4; ++i2)
      #pragma unroll
      for (int j2 = 0; j2 < 4; ++j2) {
        const int r = u + 8 * i2, c = v + 8 * j2;
        const float ph = phi[r * 32 + c];
        sr += Xr[s * 1056 + r * 33 + c] * ph;
        si += Xi[s * 1056 + r * 33 + c] * ph;
      }
    Sr[s * 72 + u * 9 + v] = sr * 0.0625f;
    Si[s * 72 + u * 9 + v] = si * 0.0625f;
  }
  __syncthreads();
  if (tid < 16) { const int s = tid >> 3, r = tid & 7; passN<8>(Sr + s * 72, Si + s * 72, r * 9, 1, 1.0f, 0, 0.0f); }
  __syncthreads();
  if (tid < 16) {
    const int s = tid >> 3, col = tid & 7;
    float2 a[8];
    #pragma unroll
    for (int i = 0; i < 8; ++i) a[i] = make_float2(Sr[s * 72 + i * 9 + col], Si[s * 72 + i * 9 + col]);
    fftN<8>(a, 1.0f);
    float* fo = feat + (size_t)(bc0 + s) * 81 * 64;
    #pragma unroll
    for (int i = 0; i < 8; ++i) fo[i * 8 + col] = a[i].x * (1.0f / 64.0f);
  }
}

// ---------------------------------------------------------------------------
// k_u0: one u0 plane per block. grid 1536 (= 192*8), block 64. ~9KB LDS.
// ---------------------------------------------------------------------------
__global__ __launch_bounds__(64) void k_u0(
    const float2* __restrict__ xf_g, const float* __restrict__ psi0,
    const float* __restrict__ phi, float2* __restrict__ u0f_g,
    float* __restrict__ feat)
{
  __shared__ float Ar[1056], Ai[1056];   // 32x33
  __shared__ float Sr[72],   Si[72];     // 8x9
  const int tid = threadIdx.x;
  const int blk = blockIdx.x;
  const int bc = blk >> 3, p = blk & 7;

  for (int e = tid; e < 1024; e += 64) {
    const float2 v = xf_g[(size_t)bc * 1024 + e];
    const float ps = psi0[p * 1024 + e];
    Ar[(e >> 5) * 33 + (e & 31)] = v.x * ps;
    Ai[(e >> 5) * 33 + (e & 31)] = v.y * ps;
  }
  __syncthreads();
  #pragma unroll 1
  for (int pp = 0; pp < 3; ++pp) {
    if (tid < 32) {
      const int so = (pp == 1) ? 1 : 33, st = 34 - so;
      const float sg = (pp == 2) ? -1.0f : 1.0f;
      const int md = (pp == 1) ? 1 : 0;
      passN<32>(Ar, Ai, tid * so, st, sg, md, 1.0f / 1024.0f);
    }
    __syncthreads();
  }
  for (int e = tid; e < 1024; e += 64) {
    u0f_g[((size_t)bc * 8 + p) * 1024 + e] =
        make_float2(Ar[(e >> 5) * 33 + (e & 31)], Ai[(e >> 5) * 33 + (e & 31)]);
  }
  { // s1a subsample (64 threads, one elem each)
    const int u = tid >> 3, v = tid & 7;
    float sr = 0.f, si = 0.f;
    #pragma unroll
    for (int i2 = 0; i2 < 4; ++i2)
      #pragma unroll
      for (int j2 = 0; j2 < 4; ++j2) {
        const int r = u + 8 * i2, c = v + 8 * j2;
        const float ph = phi[r * 32 + c];
        sr += Ar[r * 33 + c] * ph;
        si += Ai[r * 33 + c] * ph;
      }
    Sr[u * 9 + v] = sr * 0.0625f;
    Si[u * 9 + v] = si * 0.0625f;
  }
  __syncthreads();
  if (tid < 8) passN<8>(Sr, Si, tid * 9, 1, 1.0f, 0, 0.0f);
  __syncthreads();
  if (tid < 8) {
    float2 a[8];
    #pragma unroll
    for (int i = 0; i < 8; ++i) a[i] = make_float2(Sr[i * 9 + tid], Si[i * 9 + tid]);
    fftN<8>(a, 1.0f);
    float* fo = feat + ((size_t)bc * 81 + 1 + p) * 64;
    #pragma unroll
    for (int i = 0; i < 8; ++i) fo[i * 8 + tid] = a[i].x * (1.0f / 64.0f);
  }
}

// ---------------------------------------------------------------------------
// k_o2j1: one 4-plane 16x16 modulus round per block. grid 3456, block 64.
// blk: 0..383 j1 (bc x half, src xf, ch 9+); 384..3455 o2 (bc x t1 x half,
// src u0f, ch 17+t1*8+).  ~20.5KB LDS.
// ---------------------------------------------------------------------------
__global__ __launch_bounds__(64) void k_o2j1(
    const float2* __restrict__ xf_g, const float2* __restrict__ u0f_g,
    const float* __restrict__ psi1, const float* __restrict__ phi,
    float* __restrict__ feat)
{
  __shared__ float Ur[1056], Ui[1056];   // src 32x33
  __shared__ float Cr[1088], Ci[1088];   // 4 x 16x17
  __shared__ float Sr[288],  Si[288];    // 4 x 8x9
  __shared__ float P1[272];              // 16x17
  const int tid = threadIdx.x;
  const int blk = blockIdx.x;
  const int t2b = (blk & 1) * 4;
  const int sp = blk >> 1;
  const float2* src;
  int bc, chb;
  if (sp < 192) { bc = sp; src = xf_g + (size_t)sp * 1024; chb = 9 + t2b; }
  else {
    const int s2 = sp - 192;
    bc = s2 >> 3;
    const int t1 = s2 & 7;
    src = u0f_g + ((size_t)bc * 8 + t1) * 1024;
    chb = 17 + t1 * 8 + t2b;
  }

  for (int e = tid; e < 1024; e += 64) {
    const float2 v = src[e];
    Ur[(e >> 5) * 33 + (e & 31)] = v.x;
    Ui[(e >> 5) * 33 + (e & 31)] = v.y;
  }
  for (int e = tid; e < 256; e += 64) {
    const int u = e >> 4, v = e & 15;
    P1[u * 17 + v] = 0.25f * (phi[u * 32 + v] + phi[u * 32 + v + 16] +
                              phi[(u + 16) * 32 + v] + phi[(u + 16) * 32 + v + 16]);
  }
  __syncthreads();
  #pragma unroll 4
  for (int e = tid; e < 1024; e += 64) {
    const int q = e >> 8, u = (e >> 4) & 15, v = e & 15;
    const int t2 = t2b + q;
    float sr = 0.f, si = 0.f;
    #pragma unroll
    for (int i2 = 0; i2 < 2; ++i2)
      #pragma unroll
      for (int j2 = 0; j2 < 2; ++j2) {
        const int r = u + 16 * i2, c = v + 16 * j2;
        const float ps = psi1[t2 * 1024 + r * 32 + c];
        sr += Ur[r * 33 + c] * ps;
        si += Ui[r * 33 + c] * ps;
      }
    Cr[q * 272 + u * 17 + v] = 0.25f * sr;
    Ci[q * 272 + u * 17 + v] = 0.25f * si;
  }
  __syncthreads();
  #pragma unroll 1
  for (int pp = 0; pp < 3; ++pp) {
    const int q = tid >> 4, it = tid & 15;
    const int so = (pp == 1) ? 1 : 17, st = 18 - so;
    const float sg = (pp == 2) ? -1.0f : 1.0f;
    const int md = (pp == 1) ? 1 : 0;
    passN<16>(Cr + q * 272, Ci + q * 272, it * so, st, sg, md, 1.0f / 256.0f);
    __syncthreads();
  }
  for (int e = tid; e < 256; e += 64) {
    const int q = e >> 6, u = (e >> 3) & 7, v = e & 7;
    float sr = 0.f, si = 0.f;
    #pragma unroll
    for (int i2 = 0; i2 < 2; ++i2)
      #pragma unroll
      for (int j2 = 0; j2 < 2; ++j2) {
        const int r = u + 8 * i2, c = v + 8 * j2;
        const float ph = P1[r * 17 + c];
        sr += Cr[q * 272 + r * 17 + c] * ph;
        si += Ci[q * 272 + r * 17 + c] * ph;
      }
    Sr[q * 72 + u * 9 + v] = 0.25f * sr;
    Si[q * 72 + u * 9 + v] = 0.25f * si;
  }
  __syncthreads();
  if (tid < 32) { const int q = tid >> 3, r = tid & 7; passN<8>(Sr + q * 72, Si + q * 72, r * 9, 1, 1.0f, 0, 0.0f); }
  __syncthreads();
  if (tid < 32) {
    const int q = tid >> 3, col = tid & 7;
    float2 a[8];
    #pragma unroll
    for (int i = 0; i < 8; ++i) a[i] = make_float2(Sr[q * 72 + i * 9 + col], Si[q * 72 + i * 9 + col]);
    fftN<8>(a, 1.0f);
    float* fo = feat + ((size_t)bc * 81 + chb + q) * 64;
    #pragma unroll
    for (int i = 0; i < 8; ++i) fo[i * 8 + col] = a[i].x * (1.0f / 64.0f);
  }
}

// ---------------------------------------------------------------------------
// k_gnlin: GroupNorm(27) + Linear(15552->10). grid 64, block 1024.
// ---------------------------------------------------------------------------
__global__ __launch_bounds__(1024) void k_gnlin(
    const float* __restrict__ feat, const float* __restrict__ gamma,
    const float* __restrict__ beta, const float* __restrict__ W,
    const float* __restrict__ bias, float* __restrict__ out)
{
  __shared__ __align__(16) float F[15552];
  __shared__ float gmu[27], grs[27];
  __shared__ float red[160];
  const int tid = threadIdx.x, b = blockIdx.x;
  const float4* fp4 = reinterpret_cast<const float4*>(feat + (size_t)b * 15552);
  float4* F4 = reinterpret_cast<float4*>(F);
  for (int i4 = tid; i4 < 3888; i4 += 1024) F4[i4] = fp4[i4];
  __syncthreads();
  if (tid < 432) {
    const int g = tid >> 4, l = tid & 15;
    float s = 0.f, ss = 0.f;
    for (int e = l; e < 576; e += 16) { const float v = F[g * 576 + e]; s += v; ss += v * v; }
    #pragma unroll
    for (int off = 1; off < 16; off <<= 1) { s += __shfl_xor(s, off, 16); ss += __shfl_xor(ss, off, 16); }
    if (l == 0) {
      const float mu = s * (1.0f / 576.0f);
      gmu[g] = mu;
      grs[g] = rsqrtf(ss * (1.0f / 576.0f) - mu * mu + 1e-5f);
    }
  }
  __syncthreads();
  for (int e = tid; e < 15552; e += 1024) {
    const int ch = e >> 6, g = ch / 9;
    F[e] = (F[e] - gmu[g]) * grs[g] * gamma[ch] + beta[ch];
  }
  __syncthreads();
  float acc[10];
  #pragma unroll
  for (int k = 0; k < 10; ++k) acc[k] = 0.f;
  const float4* W4 = reinterpret_cast<const float4*>(W);
  for (int i4 = tid; i4 < 3888; i4 += 1024) {
    const float4 f = F4[i4];
    #pragma unroll
    for (int k = 0; k < 10; ++k) {
      const float4 w = W4[(size_t)k * 3888 + i4];
      acc[k] = fmaf(f.x, w.x, fmaf(f.y, w.y, fmaf(f.z, w.z, fmaf(f.w, w.w, acc[k]))));
    }
  }
  #pragma unroll
  for (int k = 0; k < 10; ++k) {
    float v = acc[k];
    #pragma unroll
    for (int off = 32; off > 0; off >>= 1) v += __shfl_down(v, off);
    if ((tid & 63) == 0) red[(tid >> 6) * 10 + k] = v;
  }
  __syncthreads();
  if (tid < 10) {
    float s = bias[tid];
    #pragma unroll
    for (int w = 0; w < 16; ++w) s += red[w * 10 + tid];
    out[b * 10 + tid] = s;
  }
}

// ---------------------------------------------------------------------------
extern "C" void kernel_launch(void* const* d_in, const int* in_sizes, int n_in,
                              void* d_out, int out_size, void* d_ws, size_t ws_size,
                              hipStream_t stream) {
  (void)in_sizes; (void)n_in; (void)out_size; (void)ws_size;
  const float* x     = (const float*)d_in[0];
  const float* psi0  = (const float*)d_in[1];
  const float* psi1  = (const float*)d_in[2];
  const float* phi   = (const float*)d_in[3];
  const float* gamma = (const float*)d_in[4];
  const float* beta  = (const float*)d_in[5];
  const float* W     = (const float*)d_in[6];
  const float* bias  = (const float*)d_in[7];
  float* out = (float*)d_out;

  float2* xf_g  = (float2*)d_ws;                                 // 1.5 MB
  float2* u0f_g = xf_g + (size_t)192 * 1024;                     // 12.6 MB
  float*  feat  = (float*)(u0f_g + (size_t)192 * 8 * 1024);      // 4 MB

  hipLaunchKernelGGL(k_xf,    dim3(96),   dim3(64),   0, stream, x, phi, xf_g, feat);
  hipLaunchKernelGGL(k_u0,    dim3(1536), dim3(64),   0, stream, xf_g, psi0, phi, u0f_g, feat);
  hipLaunchKernelGGL(k_o2j1,  dim3(3456), dim3(64),   0, stream, xf_g, u0f_g, psi1, phi, feat);
  hipLaunchKernelGGL(k_gnlin, dim3(64),   dim3(1024), 0, stream, feat, gamma, beta, W, bias, out);
}

// Round 10
// 123.086 us; speedup vs baseline: 1.1850x; 1.1850x over previous
//
#include <hip/hip_runtime.h>
#include <math.h>

// ---------------------------------------------------------------------------
// Scattering (J=2,L=8,N=32) + GroupNorm(27) + Linear(15552->10), round 10.
// r9 structure; FIX: Ar/Ai sized 1088 (j1 blocks use them as the 4x16x17
// C-buffer, max index 1086 — 1056 overflowed into Ai/Sr, same bug class as
// round 4's Sr overflow).
//   k_scat (1920 x 64, LDS 20736B -> 7 blocks/CU ≈ 2 waves/SIMD):
//     blocks 0..1535  : (bc,t1): fft2(x) inline, ONE u0f plane in LDS,
//                       s1a (+s0 if t1==0), then 2 rounds x 4 order-2 planes.
//     blocks 1536..1919: (bc,half): fft2(x) inline, 4 j1 planes -> s1b.
//   k_gnlin (64 x 1024): GroupNorm + GEMV(float4).
// ---------------------------------------------------------------------------

constexpr float C32T[32] = {
  1.0000000000f, 0.9807852804f, 0.9238795325f, 0.8314696123f,
  0.7071067812f, 0.5555702330f, 0.3826834324f, 0.1950903220f,
  0.0000000000f,-0.1950903220f,-0.3826834324f,-0.5555702330f,
 -0.7071067812f,-0.8314696123f,-0.9238795325f,-0.9807852804f,
 -1.0000000000f,-0.9807852804f,-0.9238795325f,-0.8314696123f,
 -0.7071067812f,-0.5555702330f,-0.3826834324f,-0.1950903220f,
  0.0000000000f, 0.1950903220f, 0.3826834324f, 0.5555702330f,
  0.7071067812f, 0.8314696123f, 0.9238795325f, 0.9807852804f };
constexpr float S32T[32] = {
  0.0000000000f, 0.1950903220f, 0.3826834324f, 0.5555702330f,
  0.7071067812f, 0.8314696123f, 0.9238795325f, 0.9807852804f,
  1.0000000000f, 0.9807852804f, 0.9238795325f, 0.8314696123f,
  0.7071067812f, 0.5555702330f, 0.3826834324f, 0.1950903220f,
  0.0000000000f,-0.1950903220f,-0.3826834324f,-0.5555702330f,
 -0.7071067812f,-0.8314696123f,-0.9238795325f,-0.9807852804f,
 -1.0000000000f,-0.9807852804f,-0.9238795325f,-0.8314696123f,
 -0.7071067812f,-0.5555702330f,-0.3826834324f,-0.1950903220f };

template<int N>
__device__ __forceinline__ void fftN(float2 (&a)[N], float sgn) {
  constexpr int LOG = (N == 32) ? 5 : ((N == 16) ? 4 : 3);
  #pragma unroll
  for (int i = 0; i < N; ++i) {
    int j = 0;
    #pragma unroll
    for (int bn = 0; bn < LOG; ++bn) j |= ((i >> bn) & 1) << (LOG - 1 - bn);
    if (j > i) { float2 t = a[i]; a[i] = a[j]; a[j] = t; }
  }
  #pragma unroll
  for (int s = 1; s <= LOG; ++s) {
    const int half  = 1 << (s - 1);
    const int tstep = 32 >> s;
    #pragma unroll
    for (int i = 0; i < N; i += (1 << s)) {
      #pragma unroll
      for (int k = 0; k < half; ++k) {
        const int ti = k * tstep;            // compile-time
        const float2 u = a[i + k];
        const float2 v = a[i + k + half];
        float tr, tq;
        if (ti == 0)      { tr = v.x;        tq = v.y; }         // w = 1
        else if (ti == 8) { tr = -sgn * v.y; tq = sgn * v.x; }   // w = i*sgn
        else {
          const float wr = C32T[ti];
          const float wi = sgn * S32T[ti];
          tr = v.x * wr - v.y * wi;
          tq = v.x * wi + v.y * wr;
        }
        a[i + k]        = make_float2(u.x + tr, u.y + tq);
        a[i + k + half] = make_float2(u.x - tr, u.y - tq);
      }
    }
  }
}

// One LDS pass: load N strided, FFT(sgn); if md: modulus*scale then forward
// FFT (rolled rep loop -> one fftN instance per call site); store back.
template<int N>
__device__ __forceinline__ void passN(float* re, float* im, int off, int st,
                                      float sgn, int md, float scale) {
  float2 a[N];
  #pragma unroll
  for (int i = 0; i < N; ++i) a[i] = make_float2(re[off + i * st], im[off + i * st]);
  #pragma unroll 1
  for (int rep = 0; rep <= md; ++rep) {
    fftN<N>(a, rep ? -1.0f : sgn);
    if (rep == 0 && md) {
      #pragma unroll
      for (int i = 0; i < N; ++i) {
        const float m = sqrtf(a[i].x * a[i].x + a[i].y * a[i].y) * scale;
        a[i] = make_float2(m, 0.0f);
      }
    }
  }
  #pragma unroll
  for (int i = 0; i < N; ++i) { re[off + i * st] = a[i].x; im[off + i * st] = a[i].y; }
}

// ---------------------------------------------------------------------------
// k_scat: grid 1920, block 64. LDS = 2*4352(XC) + 2*4352(A) + 2*1152(S)
//       + 1024(P1) = 20736 B.
// ---------------------------------------------------------------------------
__global__ __launch_bounds__(64) void k_scat(
    const float* __restrict__ x, const float* __restrict__ psi0,
    const float* __restrict__ psi1, const float* __restrict__ phi,
    float* __restrict__ feat)
{
  __shared__ float XCr[1088], XCi[1088];  // xf 32x33; later C 4x16x17 (u0 blks)
  __shared__ float Ar[1088],  Ai[1088];   // u0f plane 32x33 (u0) / C 4x16x17 (j1)
  __shared__ float Sr[288],   Si[288];    // 4 x 8x9
  __shared__ float P1[256];               // 16x16 phi at res 1
  const int tid = threadIdx.x;
  const int blk = blockIdx.x;
  const bool is_u0 = blk < 1536;
  const int bc = is_u0 ? (blk >> 3) : ((blk - 1536) >> 1);
  const int t1 = is_u0 ? (blk & 7) : 0;

  // ---- stage x, phi1; xf = fft2(x) ----
  for (int e = tid; e < 1024; e += 64) {
    XCr[(e >> 5) * 33 + (e & 31)] = x[bc * 1024 + e];
    XCi[(e >> 5) * 33 + (e & 31)] = 0.0f;
  }
  for (int e = tid; e < 256; e += 64) {
    const int u = e >> 4, v = e & 15;
    P1[u * 16 + v] = 0.25f * (phi[u * 32 + v] + phi[u * 32 + v + 16] +
                              phi[(u + 16) * 32 + v] + phi[(u + 16) * 32 + v + 16]);
  }
  __syncthreads();
  #pragma unroll 1
  for (int p = 0; p < 2; ++p) {
    if (tid < 32) {
      const int so = (p == 1) ? 1 : 33, st = 34 - so;
      passN<32>(XCr, XCi, tid * so, st, -1.0f, 0, 0.0f);
    }
    __syncthreads();
  }

  if (is_u0) {
    // ---- u0 plane t1: A = xf*psi0[t1]; 3 passes (p=1 fused modulus) ----
    for (int e = tid; e < 1024; e += 64) {
      const float ps = psi0[t1 * 1024 + e];
      const int o = (e >> 5) * 33 + (e & 31);
      Ar[o] = XCr[o] * ps;
      Ai[o] = XCi[o] * ps;
    }
    __syncthreads();
    #pragma unroll 1
    for (int pp = 0; pp < 3; ++pp) {
      if (tid < 32) {
        const int so = (pp == 1) ? 1 : 33, st = 34 - so;
        const float sg = (pp == 2) ? -1.0f : 1.0f;
        const int md = (pp == 1) ? 1 : 0;
        passN<32>(Ar, Ai, tid * so, st, sg, md, 1.0f / 1024.0f);
      }
      __syncthreads();
    }
    // ---- s1a (plane 0) + s0 (plane 1, t1==0 only); X still intact ----
    const int nsp = (t1 == 0) ? 2 : 1;
    for (int e = tid; e < nsp * 64; e += 64) {
      const int p = e >> 6, u = (e >> 3) & 7, v = e & 7;
      float sr = 0.f, si = 0.f;
      #pragma unroll
      for (int i2 = 0; i2 < 4; ++i2)
        #pragma unroll
        for (int j2 = 0; j2 < 4; ++j2) {
          const int r = u + 8 * i2, c = v + 8 * j2;
          const float ph = phi[r * 32 + c];
          float vr, vi;
          if (p == 1) { vr = XCr[r * 33 + c]; vi = XCi[r * 33 + c]; }
          else        { vr = Ar[r * 33 + c];  vi = Ai[r * 33 + c]; }
          sr += vr * ph; si += vi * ph;
        }
      Sr[p * 72 + u * 9 + v] = sr * 0.0625f;
      Si[p * 72 + u * 9 + v] = si * 0.0625f;
    }
    __syncthreads();
    if (tid < nsp * 8) { const int p = tid >> 3, r = tid & 7; passN<8>(Sr + p * 72, Si + p * 72, r * 9, 1, 1.0f, 0, 0.0f); }
    __syncthreads();
    if (tid < nsp * 8) {
      const int p = tid >> 3, col = tid & 7;
      float2 a[8];
      #pragma unroll
      for (int i = 0; i < 8; ++i) a[i] = make_float2(Sr[p * 72 + i * 9 + col], Si[p * 72 + i * 9 + col]);
      fftN<8>(a, 1.0f);
      const int ch = (p == 1) ? 0 : (1 + t1);
      float* fo = feat + ((size_t)bc * 81 + ch) * 64;
      #pragma unroll
      for (int i = 0; i < 8; ++i) fo[i * 8 + col] = a[i].x * (1.0f / 64.0f);
    }
    __syncthreads();   // S and XC(=C) about to be reused by o2 rounds
  }

  // ---- 16x16 modulus rounds: u0 blocks 2 rounds (o2), j1 blocks 1 round ----
  // u0: src = A (u0f), C = XC-space.  j1: src = XC (xf), C = A-space.
  {
    const float* ur = is_u0 ? Ar : XCr;
    const float* ui = is_u0 ? Ai : XCi;
    float* Cr = is_u0 ? XCr : Ar;
    float* Ci = is_u0 ? XCi : Ai;
    const int nr = is_u0 ? 2 : 1;
    const int t2b0 = is_u0 ? 0 : ((blk - 1536) & 1) * 4;
    #pragma unroll 1
    for (int rd = 0; rd < nr; ++rd) {
      const int t2b = is_u0 ? rd * 4 : t2b0;
      const int chb = is_u0 ? (17 + t1 * 8 + t2b) : (9 + t2b0);
      // mult + 2x2 fold
      #pragma unroll 4
      for (int e = tid; e < 1024; e += 64) {
        const int q = e >> 8, u = (e >> 4) & 15, v = e & 15;
        const int t2 = t2b + q;
        float sr = 0.f, si = 0.f;
        #pragma unroll
        for (int i2 = 0; i2 < 2; ++i2)
          #pragma unroll
          for (int j2 = 0; j2 < 2; ++j2) {
            const int r = u + 16 * i2, c = v + 16 * j2;
            const float ps = psi1[t2 * 1024 + r * 32 + c];
            sr += ur[r * 33 + c] * ps;
            si += ui[r * 33 + c] * ps;
          }
        Cr[q * 272 + u * 17 + v] = 0.25f * sr;
        Ci[q * 272 + u * 17 + v] = 0.25f * si;
      }
      __syncthreads();
      // 3 fft16 passes (p=1 fused modulus)
      #pragma unroll 1
      for (int pp = 0; pp < 3; ++pp) {
        const int q = tid >> 4, it = tid & 15;
        const int so = (pp == 1) ? 1 : 17, st = 18 - so;
        const float sg = (pp == 2) ? -1.0f : 1.0f;
        const int md = (pp == 1) ? 1 : 0;
        passN<16>(Cr + q * 272, Ci + q * 272, it * so, st, sg, md, 1.0f / 256.0f);
        __syncthreads();
      }
      // low-pass + 2x2 fold -> 8x8
      for (int e = tid; e < 256; e += 64) {
        const int q = e >> 6, u = (e >> 3) & 7, v = e & 7;
        float sr = 0.f, si = 0.f;
        #pragma unroll
        for (int i2 = 0; i2 < 2; ++i2)
          #pragma unroll
          for (int j2 = 0; j2 < 2; ++j2) {
            const int r = u + 8 * i2, c = v + 8 * j2;
            const float ph = P1[r * 16 + c];
            sr += Cr[q * 272 + r * 17 + c] * ph;
            si += Ci[q * 272 + r * 17 + c] * ph;
          }
        Sr[q * 72 + u * 9 + v] = 0.25f * sr;
        Si[q * 72 + u * 9 + v] = 0.25f * si;
      }
      __syncthreads();
      if (tid < 32) { const int q = tid >> 3, r = tid & 7; passN<8>(Sr + q * 72, Si + q * 72, r * 9, 1, 1.0f, 0, 0.0f); }
      __syncthreads();
      if (tid < 32) {
        const int q = tid >> 3, col = tid & 7;
        float2 a[8];
        #pragma unroll
        for (int i = 0; i < 8; ++i) a[i] = make_float2(Sr[q * 72 + i * 9 + col], Si[q * 72 + i * 9 + col]);
        fftN<8>(a, 1.0f);
        float* fo = feat + ((size_t)bc * 81 + chb + q) * 64;
        #pragma unroll
        for (int i = 0; i < 8; ++i) fo[i * 8 + col] = a[i].x * (1.0f / 64.0f);
      }
      __syncthreads();
    }
  }
}

// ---------------------------------------------------------------------------
// k_gnlin: GroupNorm(27) + Linear(15552->10). grid 64, block 1024.
// ---------------------------------------------------------------------------
__global__ __launch_bounds__(1024) void k_gnlin(
    const float* __restrict__ feat, const float* __restrict__ gamma,
    const float* __restrict__ beta, const float* __restrict__ W,
    const float* __restrict__ bias, float* __restrict__ out)
{
  __shared__ __align__(16) float F[15552];
  __shared__ float gmu[27], grs[27];
  __shared__ float red[160];
  const int tid = threadIdx.x, b = blockIdx.x;
  const float4* fp4 = reinterpret_cast<const float4*>(feat + (size_t)b * 15552);
  float4* F4 = reinterpret_cast<float4*>(F);
  for (int i4 = tid; i4 < 3888; i4 += 1024) F4[i4] = fp4[i4];
  __syncthreads();
  if (tid < 432) {
    const int g = tid >> 4, l = tid & 15;
    float s = 0.f, ss = 0.f;
    for (int e = l; e < 576; e += 16) { const float v = F[g * 576 + e]; s += v; ss += v * v; }
    #pragma unroll
    for (int off = 1; off < 16; off <<= 1) { s += __shfl_xor(s, off, 16); ss += __shfl_xor(ss, off, 16); }
    if (l == 0) {
      const float mu = s * (1.0f / 576.0f);
      gmu[g] = mu;
      grs[g] = rsqrtf(ss * (1.0f / 576.0f) - mu * mu + 1e-5f);
    }
  }
  __syncthreads();
  for (int e = tid; e < 15552; e += 1024) {
    const int ch = e >> 6, g = ch / 9;
    F[e] = (F[e] - gmu[g]) * grs[g] * gamma[ch] + beta[ch];
  }
  __syncthreads();
  float acc[10];
  #pragma unroll
  for (int k = 0; k < 10; ++k) acc[k] = 0.f;
  const float4* W4 = reinterpret_cast<const float4*>(W);
  for (int i4 = tid; i4 < 3888; i4 += 1024) {
    const float4 f = F4[i4];
    #pragma unroll
    for (int k = 0; k < 10; ++k) {
      const float4 w = W4[(size_t)k * 3888 + i4];
      acc[k] = fmaf(f.x, w.x, fmaf(f.y, w.y, fmaf(f.z, w.z, fmaf(f.w, w.w, acc[k]))));
    }
  }
  #pragma unroll
  for (int k = 0; k < 10; ++k) {
    float v = acc[k];
    #pragma unroll
    for (int off = 32; off > 0; off >>= 1) v += __shfl_down(v, off);
    if ((tid & 63) == 0) red[(tid >> 6) * 10 + k] = v;
  }
  __syncthreads();
  if (tid < 10) {
    float s = bias[tid];
    #pragma unroll
    for (int w = 0; w < 16; ++w) s += red[w * 10 + tid];
    out[b * 10 + tid] = s;
  }
}

// ---------------------------------------------------------------------------
extern "C" void kernel_launch(void* const* d_in, const int* in_sizes, int n_in,
                              void* d_out, int out_size, void* d_ws, size_t ws_size,
                              hipStream_t stream) {
  (void)in_sizes; (void)n_in; (void)out_size; (void)ws_size;
  const float* x     = (const float*)d_in[0];
  const float* psi0  = (const float*)d_in[1];
  const float* psi1  = (const float*)d_in[2];
  const float* phi   = (const float*)d_in[3];
  const float* gamma = (const float*)d_in[4];
  const float* beta  = (const float*)d_in[5];
  const float* W     = (const float*)d_in[6];
  const float* bias  = (const float*)d_in[7];
  float* out = (float*)d_out;

  float* feat = (float*)d_ws;   // 64*15552 f32 = 4 MB

  hipLaunchKernelGGL(k_scat,  dim3(1920), dim3(64),   0, stream, x, psi0, psi1, phi, feat);
  hipLaunchKernelGGL(k_gnlin, dim3(64),   dim3(1024), 0, stream, feat, gamma, beta, W, bias, out);
}